// Round 1
// baseline (367.284 us; speedup 1.0000x reference)
//
#include <hip/hip_runtime.h>

#define NGEN 8
#define NC 16
#define NM 256
#define NL 4
#define NNODE 21845

// float-element offsets inside d_ws
#define OFF_SMA   ((size_t)0)                                  // 8*16*16*4 = 8192
#define OFF_LSMA  ((size_t)8192)                               // 8192
#define OFF_SMB   ((size_t)16384)                              // 8*16*256 = 32768
#define OFF_LSMB  ((size_t)49152)                              // 32768
#define OFF_SMPI  ((size_t)81920)                              // 128
#define OFF_LSMPI ((size_t)82048)                              // 128
#define OFF_PRIOR ((size_t)82176)                              // 8*21845*16 = 2796160
#define OFF_BETA  (OFF_PRIOR + (size_t)NGEN*NNODE*NC)
#define OFF_BETAIL (OFF_BETA + (size_t)NGEN*NNODE*NC)
// eps_i aliases beta_i: each thread reads its own beta[u,i] before writing
// eps[u,i]; parent entries already hold eps when a level runs. Saves 11 MB.
#define OFF_EPS   OFF_BETA

__device__ __forceinline__ float red16(float v) {
    v += __shfl_xor(v, 1, 16);
    v += __shfl_xor(v, 2, 16);
    v += __shfl_xor(v, 4, 16);
    v += __shfl_xor(v, 8, 16);
    return v;
}

__global__ void k_zero(float* out) { out[threadIdx.x] = 0.0f; }

// one block per gen: softmax of a (64 columns over i=16) + pi (1 thread)
__global__ void k_pre(const float* __restrict__ a, const float* __restrict__ pi,
                      float* __restrict__ ws) {
    int g = blockIdx.x;
    int tid = threadIdx.x;
    if (tid < 64) {
        int j = tid >> 2, l = tid & 3;
        size_t base = ((size_t)(g * NC) * NC + j) * NL + l;  // i-stride = NC*NL = 64
        float v[16];
        float mx = -1e30f;
#pragma unroll
        for (int i = 0; i < 16; ++i) { v[i] = a[base + (size_t)i * NC * NL]; mx = fmaxf(mx, v[i]); }
        float e[16], s = 0.0f;
#pragma unroll
        for (int i = 0; i < 16; ++i) { e[i] = expf(v[i] - mx); s += e[i]; }
        float ls = logf(s);
#pragma unroll
        for (int i = 0; i < 16; ++i) {
            ws[OFF_SMA + base + (size_t)i * NC * NL] = e[i] / s;
            ws[OFF_LSMA + base + (size_t)i * NC * NL] = v[i] - mx - ls;
        }
    } else if (tid == 64) {
        float v[16];
        float mx = -1e30f;
#pragma unroll
        for (int i = 0; i < 16; ++i) { v[i] = pi[g * NC + i]; mx = fmaxf(mx, v[i]); }
        float e[16], s = 0.0f;
#pragma unroll
        for (int i = 0; i < 16; ++i) { e[i] = expf(v[i] - mx); s += e[i]; }
        float ls = logf(s);
#pragma unroll
        for (int i = 0; i < 16; ++i) {
            float sm = e[i] / s;
            ws[OFF_SMPI + g * NC + i] = sm;
            ws[OFF_LSMPI + g * NC + i] = v[i] - mx - ls;
            ws[OFF_PRIOR + ((size_t)g * NNODE) * NC + i] = sm;  // prior at root = sm_pi
        }
    }
}

// one block per (g,i): softmax over M=256
__global__ void k_softmax_b(const float* __restrict__ b, float* __restrict__ ws) {
    int gi = blockIdx.x;
    int g = gi >> 4, i = gi & 15;
    int m = threadIdx.x;
    float v = b[((size_t)(g * NC + i)) * NM + m];
    __shared__ float sred[256];
    sred[m] = v;
    __syncthreads();
    for (int s = 128; s > 0; s >>= 1) { if (m < s) sred[m] = fmaxf(sred[m], sred[m + s]); __syncthreads(); }
    float mx = sred[0];
    __syncthreads();
    float ex = expf(v - mx);
    sred[m] = ex;
    __syncthreads();
    for (int s = 128; s > 0; s >>= 1) { if (m < s) sred[m] += sred[m + s]; __syncthreads(); }
    float sum = sred[0];
    ws[OFF_SMB + ((size_t)(g * NC + i)) * NM + m] = ex / sum;
    ws[OFF_LSMB + ((size_t)(g * NC + i)) * NM + m] = v - mx - logf(sum);
}

// prior[g,u,i] = sum_j sm_a[g,i,j,pos(u)] * prior[g,pa(u),j]
__global__ __launch_bounds__(256) void k_prior(float* __restrict__ ws, int lo, int size) {
    int g = blockIdx.y;
    int idx = blockIdx.x * 256 + threadIdx.x;
    int u_rel = idx >> 4, i = idx & 15;
    if (u_rel >= size) return;
    int u = lo + u_rel;
    int pa = (u - 1) >> 2, pos = (u - 1) & 3;
    const float* sma = ws + OFF_SMA + ((size_t)(g * NC + i)) * NC * NL + pos;
    const float* pp = ws + OFF_PRIOR + ((size_t)g * NNODE + pa) * NC;
    float s = 0.0f;
#pragma unroll
    for (int j = 0; j < 16; ++j) s += sma[(size_t)j * NL] * pp[j];
    ws[OFF_PRIOR + ((size_t)g * NNODE + u) * NC + i] = s;
}

__global__ __launch_bounds__(256) void k_leaf(float* __restrict__ ws, const int* __restrict__ t,
                                              int lo, int size) {
    int g = blockIdx.y;
    int idx = blockIdx.x * 256 + threadIdx.x;
    int u_rel = idx >> 4, i = idx & 15;
    if (u_rel >= size) return;
    int u = lo + u_rel;
    int lab = t[u * 7];
    size_t nb = ((size_t)g * NNODE + u) * NC;
    float v = ws[OFF_SMB + ((size_t)(g * NC + i)) * NM + lab] * ws[OFF_PRIOR + nb + i];
    float s = red16(v);
    ws[OFF_BETA + nb + i] = v / s;
}

// upward: per internal node, bil over 4 children; beta_il scatter; beta_i update
__global__ __launch_bounds__(256) void k_up(float* __restrict__ ws, const int* __restrict__ t,
                                            int lo, int size) {
    int g = blockIdx.y, tid = threadIdx.x;
    __shared__ float lds_a[NC][NC][NL];   // sm_a[g][c][p][l]
    __shared__ float lds_r[16][NL][NC];   // ratio[node][l][c]
    for (int k = tid; k < NC * NC * NL; k += 256)
        (&lds_a[0][0][0])[k] = ws[OFF_SMA + (size_t)g * NC * NC * NL + k];
    int node0 = blockIdx.x * 16;
    for (int e = tid; e < 1024; e += 256) {
        int nd = e >> 6, l = (e >> 4) & 3, c = e & 15;
        if (node0 + nd < size) {
            int u = lo + node0 + nd;
            size_t cb = ((size_t)g * NNODE + 4 * u + 1 + l) * NC + c;
            lds_r[nd][l][c] = ws[OFF_BETA + cb] / ws[OFF_PRIOR + cb];
        }
    }
    __syncthreads();
    int nd = tid >> 4, p = tid & 15;
    int u_rel = node0 + nd;
    if (u_rel >= size) return;
    int u = lo + u_rel;
    float aux = 1.0f;
#pragma unroll
    for (int l = 0; l < 4; ++l) {
        float bil = 0.0f;
#pragma unroll
        for (int c = 0; c < 16; ++c) bil += lds_r[nd][l][c] * lds_a[c][p][l];
        ws[OFF_BETAIL + ((size_t)g * NNODE + 4 * u + 1 + l) * NC + p] = bil;
        aux *= bil;
    }
    int lab = t[u * 7];
    size_t nb = ((size_t)g * NNODE + u) * NC;
    float bi = aux * ws[OFF_SMB + ((size_t)(g * NC + p)) * NM + lab] * ws[OFF_PRIOR + nb + p];
    float s = red16(bi);
    ws[OFF_BETA + nb + p] = bi / s;
}

// root: eps[0]=beta[0]; accumulate pi_lh + root b-term
__global__ void k_root(float* __restrict__ ws, const int* __restrict__ t, float* __restrict__ out) {
    int g = blockIdx.x, i = threadIdx.x;  // 16 threads
    size_t nb = ((size_t)g * NNODE) * NC;
    float e = ws[OFF_BETA + nb + i];
    ws[OFF_EPS + nb + i] = e;
    int lab0 = t[0];
    float val = e * (ws[OFF_LSMPI + g * NC + i] + ws[OFF_LSMB + ((size_t)(g * NC + i)) * NM + lab0]);
    float s = red16(val);
    if (i == 0) atomicAdd(&out[g], s);
}

// downward: eps + fused a_lh/b_lh accumulation
__global__ __launch_bounds__(256) void k_down(float* __restrict__ ws, const int* __restrict__ t,
                                              int lo, int size, float* __restrict__ out) {
    int g = blockIdx.y, tid = threadIdx.x;
    int idx = blockIdx.x * 256 + tid;
    int u_rel = idx >> 4, i = idx & 15;
    float acc = 0.0f;
    if (u_rel < size) {
        int u = lo + u_rel;
        int pa = (u - 1) >> 2, pos = (u - 1) & 3;
        int lab = t[u * 7];
        size_t nb = ((size_t)g * NNODE + u) * NC;
        float bi_u = ws[OFF_BETA + nb + i];
        float pr = ws[OFF_PRIOR + nb + i];
        const float* sma = ws + OFF_SMA + ((size_t)(g * NC + i)) * NC * NL + pos;
        const float* lsma = ws + OFF_LSMA + ((size_t)(g * NC + i)) * NC * NL + pos;
        const float* epsP = ws + OFF_EPS + ((size_t)g * NNODE + pa) * NC;
        const float* bil = ws + OFF_BETAIL + nb;
        float esum = 0.0f;
#pragma unroll
        for (int j = 0; j < 16; ++j) {
            float e = bi_u * sma[(size_t)j * NL] * epsP[j] / (pr * bil[j]);
            esum += e;
            acc += e * lsma[(size_t)j * NL];
        }
        float tot = red16(esum);
        float ev = esum / tot;
        ws[OFF_EPS + nb + i] = ev;
        acc += ev * ws[OFF_LSMB + ((size_t)(g * NC + i)) * NM + lab];
    }
    __shared__ float sred[256];
    sred[tid] = acc;
    __syncthreads();
    for (int s = 128; s > 0; s >>= 1) { if (tid < s) sred[tid] += sred[tid + s]; __syncthreads(); }
    if (tid == 0) atomicAdd(&out[g], sred[0]);
}

extern "C" void kernel_launch(void* const* d_in, const int* in_sizes, int n_in,
                              void* d_out, int out_size, void* d_ws, size_t ws_size,
                              hipStream_t stream) {
    const float* a = (const float*)d_in[0];
    const float* b = (const float*)d_in[1];
    const float* pi = (const float*)d_in[2];
    const int* t = (const int*)d_in[3];
    float* out = (float*)d_out;
    float* ws = (float*)d_ws;
    static const int LIM[9] = {0, 1, 5, 21, 85, 341, 1365, 5461, 21845};

    k_zero<<<1, 8, 0, stream>>>(out);
    k_pre<<<NGEN, 128, 0, stream>>>(a, pi, ws);
    k_softmax_b<<<NGEN * NC, 256, 0, stream>>>(b, ws);

    for (int lev = 1; lev < 8; ++lev) {
        int lo = LIM[lev], size = LIM[lev + 1] - lo;
        dim3 grid((size + 15) / 16, NGEN);
        k_prior<<<grid, 256, 0, stream>>>(ws, lo, size);
    }
    {
        int lo = LIM[7], size = LIM[8] - LIM[7];
        dim3 grid((size + 15) / 16, NGEN);
        k_leaf<<<grid, 256, 0, stream>>>(ws, t, lo, size);
    }
    for (int lev = 6; lev >= 0; --lev) {
        int lo = LIM[lev], size = LIM[lev + 1] - lo;
        dim3 grid((size + 15) / 16, NGEN);
        k_up<<<grid, 256, 0, stream>>>(ws, t, lo, size);
    }
    k_root<<<NGEN, 16, 0, stream>>>(ws, t, out);
    for (int lev = 1; lev < 8; ++lev) {
        int lo = LIM[lev], size = LIM[lev + 1] - lo;
        dim3 grid((size + 15) / 16, NGEN);
        k_down<<<grid, 256, 0, stream>>>(ws, t, lo, size, out);
    }
}

// Round 2
// 255.332 us; speedup vs baseline: 1.4385x; 1.4385x over previous
//
#include <hip/hip_runtime.h>

#define NGEN 8
#define NC 16
#define NM 256
#define NL 4
#define NNODE 21845

// float-element offsets inside d_ws
#define OFF_SMA_T  ((size_t)0)            // [g][j][l][i]  8*16*4*16 = 8192
#define OFF_LSMA_T ((size_t)8192)         // [g][j][l][i]  8192
#define OFF_SMA_U  ((size_t)16384)        // [g][c][l][p]  8192 (for k_up)
#define OFF_SMB_T  ((size_t)24576)        // [g][m][i]     8*256*16 = 32768
#define OFF_LSMB_T ((size_t)57344)        // 32768
#define OFF_SMPI   ((size_t)90112)        // 128
#define OFF_LSMPI  ((size_t)90240)        // 128
#define OFF_PRIOR  ((size_t)90368)        // 8*21845*16 = 2796160
#define OFF_BETA   (OFF_PRIOR + (size_t)NGEN*NNODE*NC)
#define OFF_BETAIL (OFF_BETA + (size_t)NGEN*NNODE*NC)
// eps_i aliases beta_i: each thread reads its own beta[u,i] before writing
// eps[u,i]; parent levels already hold eps when a level runs.
#define OFF_EPS    OFF_BETA

__device__ __forceinline__ float red16(float v) {
    v += __shfl_xor(v, 1, 16);
    v += __shfl_xor(v, 2, 16);
    v += __shfl_xor(v, 4, 16);
    v += __shfl_xor(v, 8, 16);
    return v;
}
__device__ __forceinline__ float rcpf(float x) { return __builtin_amdgcn_rcpf(x); }

__global__ void k_zero(float* out) { out[threadIdx.x] = 0.0f; }

// one block per gen: softmax of a (64 columns over i=16) + pi (1 thread)
__global__ void k_pre(const float* __restrict__ a, const float* __restrict__ pi,
                      float* __restrict__ ws) {
    int g = blockIdx.x;
    int tid = threadIdx.x;
    if (tid < 64) {
        int j = tid >> 2, l = tid & 3;
        size_t base = ((size_t)(g * NC) * NC + j) * NL + l;  // a[g][i][j][l], i-stride 64
        float v[16];
        float mx = -1e30f;
#pragma unroll
        for (int i = 0; i < 16; ++i) { v[i] = a[base + (size_t)i * NC * NL]; mx = fmaxf(mx, v[i]); }
        float e[16], s = 0.0f;
#pragma unroll
        for (int i = 0; i < 16; ++i) { e[i] = expf(v[i] - mx); s += e[i]; }
        float ls = logf(s);
        float rs = 1.0f / s;
        size_t tb = ((size_t)(g * NC + j) * NL + l) * NC;  // [g][j][l][*]
#pragma unroll
        for (int i = 0; i < 16; ++i) {
            float sm = e[i] * rs;
            ws[OFF_SMA_T + tb + i] = sm;
            ws[OFF_LSMA_T + tb + i] = v[i] - mx - ls;
            ws[OFF_SMA_U + ((size_t)(g * NC + i) * NL + l) * NC + j] = sm;  // [g][c][l][p]
        }
    } else if (tid == 64) {
        float v[16];
        float mx = -1e30f;
#pragma unroll
        for (int i = 0; i < 16; ++i) { v[i] = pi[g * NC + i]; mx = fmaxf(mx, v[i]); }
        float e[16], s = 0.0f;
#pragma unroll
        for (int i = 0; i < 16; ++i) { e[i] = expf(v[i] - mx); s += e[i]; }
        float ls = logf(s);
        float rs = 1.0f / s;
#pragma unroll
        for (int i = 0; i < 16; ++i) {
            float sm = e[i] * rs;
            ws[OFF_SMPI + g * NC + i] = sm;
            ws[OFF_LSMPI + g * NC + i] = v[i] - mx - ls;
            ws[OFF_PRIOR + ((size_t)g * NNODE) * NC + i] = sm;  // prior at root = sm_pi
        }
    }
}

// one block per (g,i): softmax over M=256; writes TRANSPOSED [g][m][i]
__global__ void k_softmax_b(const float* __restrict__ b, float* __restrict__ ws) {
    int gi = blockIdx.x;
    int g = gi >> 4, i = gi & 15;
    int m = threadIdx.x;
    float v = b[((size_t)(g * NC + i)) * NM + m];
    __shared__ float sred[256];
    sred[m] = v;
    __syncthreads();
    for (int s = 128; s > 0; s >>= 1) { if (m < s) sred[m] = fmaxf(sred[m], sred[m + s]); __syncthreads(); }
    float mx = sred[0];
    __syncthreads();
    float ex = expf(v - mx);
    sred[m] = ex;
    __syncthreads();
    for (int s = 128; s > 0; s >>= 1) { if (m < s) sred[m] += sred[m + s]; __syncthreads(); }
    float sum = sred[0];
    ws[OFF_SMB_T + ((size_t)g * NM + m) * NC + i] = ex / sum;
    ws[OFF_LSMB_T + ((size_t)g * NM + m) * NC + i] = v - mx - logf(sum);
}

// prior[g,u,i] = sum_j sm_a[g,i,j,pos(u)] * prior[g,pa(u),j]
__global__ __launch_bounds__(256) void k_prior(float* __restrict__ ws, int lo, int size) {
    int g = blockIdx.y, tid = threadIdx.x;
    __shared__ float sA[16][4][16];  // [j][pos][i]
    for (int k = tid; k < 1024; k += 256)
        (&sA[0][0][0])[k] = ws[OFF_SMA_T + (size_t)g * 1024 + k];
    __syncthreads();
    int idx = blockIdx.x * 256 + tid;
    int u_rel = idx >> 4, i = idx & 15;
    if (u_rel >= size) return;
    int u = lo + u_rel;
    int pa = (u - 1) >> 2, pos = (u - 1) & 3;
    const float* pp = ws + OFF_PRIOR + ((size_t)g * NNODE + pa) * NC;
    float s = 0.0f;
#pragma unroll
    for (int j = 0; j < 16; ++j) s += sA[j][pos][i] * pp[j];
    ws[OFF_PRIOR + ((size_t)g * NNODE + u) * NC + i] = s;
}

__global__ __launch_bounds__(256) void k_leaf(float* __restrict__ ws, const int* __restrict__ t,
                                              int lo, int size) {
    int g = blockIdx.y;
    int idx = blockIdx.x * 256 + threadIdx.x;
    int u_rel = idx >> 4, i = idx & 15;
    if (u_rel >= size) return;
    int u = lo + u_rel;
    int lab = t[u * 7];
    size_t nb = ((size_t)g * NNODE + u) * NC;
    float v = ws[OFF_SMB_T + ((size_t)g * NM + lab) * NC + i] * ws[OFF_PRIOR + nb + i];
    float s = red16(v);
    ws[OFF_BETA + nb + i] = v * rcpf(s);
}

// upward: per internal node, bil over 4 children; beta_il scatter; beta_i update
__global__ __launch_bounds__(256) void k_up(float* __restrict__ ws, const int* __restrict__ t,
                                            int lo, int size) {
    int g = blockIdx.y, tid = threadIdx.x;
    __shared__ float lds_a[NC][NL][NC];      // [c][l][p] = sm_a[g][c][p][l]
    __shared__ float lds_r[16][NL][NC + 1];  // ratio[node][l][c], padded
    for (int k = tid; k < NC * NC * NL; k += 256)
        (&lds_a[0][0][0])[k] = ws[OFF_SMA_U + (size_t)g * 1024 + k];
    int node0 = blockIdx.x * 16;
    for (int e = tid; e < 1024; e += 256) {
        int nd = e >> 6, l = (e >> 4) & 3, c = e & 15;
        if (node0 + nd < size) {
            int u = lo + node0 + nd;
            size_t cb = ((size_t)g * NNODE + 4 * u + 1 + l) * NC + c;
            lds_r[nd][l][c] = ws[OFF_BETA + cb] * rcpf(ws[OFF_PRIOR + cb]);
        }
    }
    __syncthreads();
    int nd = tid >> 4, p = tid & 15;
    int u_rel = node0 + nd;
    if (u_rel >= size) return;
    int u = lo + u_rel;
    float aux = 1.0f;
#pragma unroll
    for (int l = 0; l < 4; ++l) {
        float bil = 0.0f;
#pragma unroll
        for (int c = 0; c < 16; ++c) bil += lds_r[nd][l][c] * lds_a[c][l][p];
        ws[OFF_BETAIL + ((size_t)g * NNODE + 4 * u + 1 + l) * NC + p] = bil;
        aux *= bil;
    }
    int lab = t[u * 7];
    size_t nb = ((size_t)g * NNODE + u) * NC;
    float bi = aux * ws[OFF_SMB_T + ((size_t)g * NM + lab) * NC + p] * ws[OFF_PRIOR + nb + p];
    float s = red16(bi);
    ws[OFF_BETA + nb + p] = bi * rcpf(s);
}

// root: eps[0]=beta[0]; accumulate pi_lh + root b-term
__global__ void k_root(float* __restrict__ ws, const int* __restrict__ t, float* __restrict__ out) {
    int g = blockIdx.x, i = threadIdx.x;  // 16 threads
    size_t nb = ((size_t)g * NNODE) * NC;
    float e = ws[OFF_BETA + nb + i];
    ws[OFF_EPS + nb + i] = e;
    int lab0 = t[0];
    float val = e * (ws[OFF_LSMPI + g * NC + i] + ws[OFF_LSMB_T + ((size_t)g * NM + lab0) * NC + i]);
    float s = red16(val);
    if (i == 0) atomicAdd(&out[g], s);
}

// downward: eps + fused a_lh/b_lh accumulation
__global__ __launch_bounds__(256) void k_down(float* __restrict__ ws, const int* __restrict__ t,
                                              int lo, int size, float* __restrict__ out) {
    int g = blockIdx.y, tid = threadIdx.x;
    __shared__ float sA[16][4][16], lA[16][4][16];  // [j][pos][i]
    for (int k = tid; k < 1024; k += 256) {
        (&sA[0][0][0])[k] = ws[OFF_SMA_T + (size_t)g * 1024 + k];
        (&lA[0][0][0])[k] = ws[OFF_LSMA_T + (size_t)g * 1024 + k];
    }
    __syncthreads();
    int idx = blockIdx.x * 256 + tid;
    int u_rel = idx >> 4, i = idx & 15;
    float acc = 0.0f;
    if (u_rel < size) {
        int u = lo + u_rel;
        int pa = (u - 1) >> 2, pos = (u - 1) & 3;
        int lab = t[u * 7];
        size_t nb = ((size_t)g * NNODE + u) * NC;
        float bi_u = ws[OFF_BETA + nb + i];
        float pr = ws[OFF_PRIOR + nb + i];
        const float* epsP = ws + OFF_EPS + ((size_t)g * NNODE + pa) * NC;
        const float* bil = ws + OFF_BETAIL + nb;
        float c0 = bi_u * rcpf(pr);
        float esum = 0.0f;
#pragma unroll
        for (int j = 0; j < 16; ++j) {
            float e = c0 * sA[j][pos][i] * epsP[j] * rcpf(bil[j]);
            esum += e;
            acc += e * lA[j][pos][i];
        }
        float tot = red16(esum);
        float ev = esum * rcpf(tot);
        ws[OFF_EPS + nb + i] = ev;
        acc += ev * ws[OFF_LSMB_T + ((size_t)g * NM + lab) * NC + i];
    }
    // reduce acc across the block: wave shfl + 4-slot LDS
#pragma unroll
    for (int o = 1; o < 64; o <<= 1) acc += __shfl_xor(acc, o, 64);
    __shared__ float wsum[4];
    if ((tid & 63) == 0) wsum[tid >> 6] = acc;
    __syncthreads();
    if (tid == 0) atomicAdd(&out[g], wsum[0] + wsum[1] + wsum[2] + wsum[3]);
}

extern "C" void kernel_launch(void* const* d_in, const int* in_sizes, int n_in,
                              void* d_out, int out_size, void* d_ws, size_t ws_size,
                              hipStream_t stream) {
    const float* a = (const float*)d_in[0];
    const float* b = (const float*)d_in[1];
    const float* pi = (const float*)d_in[2];
    const int* t = (const int*)d_in[3];
    float* out = (float*)d_out;
    float* ws = (float*)d_ws;
    static const int LIM[9] = {0, 1, 5, 21, 85, 341, 1365, 5461, 21845};

    k_zero<<<1, 8, 0, stream>>>(out);
    k_pre<<<NGEN, 128, 0, stream>>>(a, pi, ws);
    k_softmax_b<<<NGEN * NC, 256, 0, stream>>>(b, ws);

    for (int lev = 1; lev < 8; ++lev) {
        int lo = LIM[lev], size = LIM[lev + 1] - lo;
        dim3 grid((size + 15) / 16, NGEN);
        k_prior<<<grid, 256, 0, stream>>>(ws, lo, size);
    }
    {
        int lo = LIM[7], size = LIM[8] - LIM[7];
        dim3 grid((size + 15) / 16, NGEN);
        k_leaf<<<grid, 256, 0, stream>>>(ws, t, lo, size);
    }
    for (int lev = 6; lev >= 0; --lev) {
        int lo = LIM[lev], size = LIM[lev + 1] - lo;
        dim3 grid((size + 15) / 16, NGEN);
        k_up<<<grid, 256, 0, stream>>>(ws, t, lo, size);
    }
    k_root<<<NGEN, 16, 0, stream>>>(ws, t, out);
    for (int lev = 1; lev < 8; ++lev) {
        int lo = LIM[lev], size = LIM[lev + 1] - lo;
        dim3 grid((size + 15) / 16, NGEN);
        k_down<<<grid, 256, 0, stream>>>(ws, t, lo, size, out);
    }
}

// Round 3
// 200.606 us; speedup vs baseline: 1.8309x; 1.2728x over previous
//
#include <hip/hip_runtime.h>

#define NGEN 8
#define NC 16
#define NM 256
#define NNODE 21845

// float-element offsets inside d_ws
#define OFF_SMA_T  ((size_t)0)            // [g][j][l][i] sm_a           8192
#define OFF_SALA   ((size_t)8192)         // [g][j][l][i] sm_a*log(sm_a) 8192
#define OFF_SMA_U  ((size_t)16384)        // [g][c][l][p] sm_a           8192
#define OFF_SMB_T  ((size_t)24576)        // [g][m][i]                   32768
#define OFF_LSMB_T ((size_t)57344)        // [g][m][i] log               32768
#define OFF_SMPI   ((size_t)90112)        // 128
#define OFF_LSMPI  ((size_t)90240)        // 128
#define OFF_PRIOR  ((size_t)90368)        // 8*21845*16
#define OFF_BETA   (OFF_PRIOR + (size_t)NGEN*NNODE*NC)
#define OFF_BETAIL (OFF_BETA + (size_t)NGEN*NNODE*NC)
#define OFF_EPS    OFF_BETA   // eps aliases beta (each elem read-then-written by its own thread)

__device__ __forceinline__ float red16(float v) {
    v += __shfl_xor(v, 1, 16);
    v += __shfl_xor(v, 2, 16);
    v += __shfl_xor(v, 4, 16);
    v += __shfl_xor(v, 8, 16);
    return v;
}
__device__ __forceinline__ float rcpf(float x) { return __builtin_amdgcn_rcpf(x); }

// ---- init: softmax_b (blocks 0..127), softmax_a+pi+zero (blocks 128..135) ----
__global__ __launch_bounds__(256) void k_init(const float* __restrict__ a,
                                              const float* __restrict__ b,
                                              const float* __restrict__ pi,
                                              float* __restrict__ ws, float* __restrict__ out) {
    int bx = blockIdx.x, tid = threadIdx.x;
    if (bx < 128) {
        int g = bx >> 4, i = bx & 15, m = tid;
        float v = b[((size_t)(g * NC + i)) * NM + m];
        __shared__ float sred[256];
        sred[m] = v;
        __syncthreads();
        for (int s = 128; s > 0; s >>= 1) { if (m < s) sred[m] = fmaxf(sred[m], sred[m + s]); __syncthreads(); }
        float mx = sred[0];
        __syncthreads();
        float ex = expf(v - mx);
        sred[m] = ex;
        __syncthreads();
        for (int s = 128; s > 0; s >>= 1) { if (m < s) sred[m] += sred[m + s]; __syncthreads(); }
        float sum = sred[0];
        ws[OFF_SMB_T + ((size_t)g * NM + m) * NC + i] = ex / sum;
        ws[OFF_LSMB_T + ((size_t)g * NM + m) * NC + i] = v - mx - logf(sum);
        return;
    }
    int g = bx - 128;
    if (tid < 64) {
        int j = tid >> 2, l = tid & 3;
        size_t base = ((size_t)(g * NC) * NC + j) * 4 + l;  // a[g][i][j][l], i-stride 64
        float v[16];
        float mx = -1e30f;
#pragma unroll
        for (int i = 0; i < 16; ++i) { v[i] = a[base + (size_t)i * 64]; mx = fmaxf(mx, v[i]); }
        float e[16], s = 0.0f;
#pragma unroll
        for (int i = 0; i < 16; ++i) { e[i] = expf(v[i] - mx); s += e[i]; }
        float ls = logf(s), rs = 1.0f / s;
        size_t tb = ((size_t)(g * NC + j) * 4 + l) * NC;  // [g][j][l][*]
#pragma unroll
        for (int i = 0; i < 16; ++i) {
            float sm = e[i] * rs;
            float lg = v[i] - mx - ls;
            ws[OFF_SMA_T + tb + i] = sm;
            ws[OFF_SALA + tb + i] = sm * lg;
            ws[OFF_SMA_U + ((size_t)(g * NC + i) * 4 + l) * NC + j] = sm;  // [g][c][l][p]
        }
    } else if (tid == 64) {
        float v[16];
        float mx = -1e30f;
#pragma unroll
        for (int i = 0; i < 16; ++i) { v[i] = pi[g * NC + i]; mx = fmaxf(mx, v[i]); }
        float e[16], s = 0.0f;
#pragma unroll
        for (int i = 0; i < 16; ++i) { e[i] = expf(v[i] - mx); s += e[i]; }
        float ls = logf(s), rs = 1.0f / s;
#pragma unroll
        for (int i = 0; i < 16; ++i) {
            float sm = e[i] * rs;
            ws[OFF_SMPI + g * NC + i] = sm;
            ws[OFF_LSMPI + g * NC + i] = v[i] - mx - ls;
            ws[OFF_PRIOR + ((size_t)g * NNODE) * NC + i] = sm;
        }
        out[g] = 0.0f;
    }
}

// ---- prior levels 1..5, one block per gen ----
__global__ __launch_bounds__(256) void k_prior_small(float* __restrict__ ws) {
    int g = blockIdx.x, tid = threadIdx.x;
    __shared__ float sA[1024];
    for (int k = tid; k < 1024; k += 256) sA[k] = ws[OFF_SMA_T + (size_t)g * 1024 + k];
    __syncthreads();
    constexpr int LIM[9] = {0, 1, 5, 21, 85, 341, 1365, 5461, 21845};
    for (int lev = 1; lev <= 5; ++lev) {
        int lo = LIM[lev];
        int elems = (LIM[lev + 1] - lo) * 16;
        for (int idx = tid; idx < elems; idx += 256) {
            int u = lo + (idx >> 4), i = idx & 15;
            int pa = (u - 1) >> 2, pos = (u - 1) & 3;
            float pv = ws[OFF_PRIOR + ((size_t)g * NNODE + pa) * NC + i];
            float s = 0.0f;
#pragma unroll
            for (int j = 0; j < 16; ++j) s += sA[(j * 4 + pos) * 16 + i] * __shfl(pv, j, 16);
            ws[OFF_PRIOR + ((size_t)g * NNODE + u) * NC + i] = s;
        }
        __syncthreads();
    }
}

// ---- prior big level (grid-stride, pos-constant hoisted sm_a); LEAF fuses beta init ----
template <bool LEAF>
__global__ __launch_bounds__(256) void k_prior_big(float* __restrict__ ws, const int* __restrict__ t,
                                                   int lo, int elems) {
    int g = blockIdx.y, tid = threadIdx.x;
    int idx0 = blockIdx.x * 256 + tid;
    int stride = gridDim.x * 256;
    int i = tid & 15;
    int pos = (lo + (idx0 >> 4) - 1) & 3;  // invariant: stride/16 nodes is a multiple of 4
    float sAreg[16];
#pragma unroll
    for (int j = 0; j < 16; ++j) sAreg[j] = ws[OFF_SMA_T + (size_t)g * 1024 + (j * 4 + pos) * 16 + i];
    for (int idx = idx0; idx < elems; idx += stride) {
        int u = lo + (idx >> 4);
        int pa = (u - 1) >> 2;
        size_t nb = ((size_t)g * NNODE + u) * NC;
        float pv = ws[OFF_PRIOR + ((size_t)g * NNODE + pa) * NC + i];
        float s = 0.0f;
#pragma unroll
        for (int j = 0; j < 16; ++j) s += sAreg[j] * __shfl(pv, j, 16);
        ws[OFF_PRIOR + nb + i] = s;
        if (LEAF) {
            int lab = t[u * 7];
            float v = ws[OFF_SMB_T + ((size_t)g * NM + lab) * NC + i] * s;
            float sum = red16(v);
            ws[OFF_BETA + nb + i] = v * rcpf(sum);
        }
    }
}

// ---- up-pass body: one wave per node; lane = (l,p); A[c][l][p] hoisted ----
__device__ __forceinline__ void up_node(float* __restrict__ ws, const int* __restrict__ t,
                                        int g, int u, int l, int p, int lane, const float* Areg) {
    size_t chb = ((size_t)g * NNODE + 4 * u + 1) * NC;
    float bv = ws[OFF_BETA + chb + lane];
    float pv = ws[OFF_PRIOR + chb + lane];
    float rv = bv * rcpf(pv);  // r[child l][state c] at lane l*16+c
    float bil = 0.0f;
#pragma unroll
    for (int c = 0; c < 16; ++c) bil += __shfl(rv, c, 16) * Areg[c];
    ws[OFF_BETAIL + chb + lane] = bil;
    float t0 = bil * __shfl_xor(bil, 16, 64);
    float aux = t0 * __shfl_xor(t0, 32, 64);
    int lab = t[u * 7];
    size_t nb = ((size_t)g * NNODE + u) * NC;
    float bi = aux * ws[OFF_SMB_T + ((size_t)g * NM + lab) * NC + p] * ws[OFF_PRIOR + nb + p];
    float sum = red16(bi);
    if (l == 0) ws[OFF_BETA + nb + p] = bi * rcpf(sum);
}

__global__ __launch_bounds__(256) void k_up_big(float* __restrict__ ws, const int* __restrict__ t,
                                                int lo, int nodes) {
    int g = blockIdx.y, tid = threadIdx.x;
    int lane = tid & 63, wid = tid >> 6;
    int l = lane >> 4, p = lane & 15;
    float Areg[16];
#pragma unroll
    for (int c = 0; c < 16; ++c) Areg[c] = ws[OFF_SMA_U + (size_t)g * 1024 + (c * 4 + l) * 16 + p];
    int stride = gridDim.x * 4;
    for (int n = blockIdx.x * 4 + wid; n < nodes; n += stride)
        up_node(ws, t, g, lo + n, l, p, lane, Areg);
}

// ---- up levels 4..0, one block per gen (16 waves) ----
__global__ __launch_bounds__(1024) void k_up_small(float* __restrict__ ws, const int* __restrict__ t) {
    int g = blockIdx.x, tid = threadIdx.x;
    int lane = tid & 63, wid = tid >> 6;
    int l = lane >> 4, p = lane & 15;
    float Areg[16];
#pragma unroll
    for (int c = 0; c < 16; ++c) Areg[c] = ws[OFF_SMA_U + (size_t)g * 1024 + (c * 4 + l) * 16 + p];
    constexpr int LIM[9] = {0, 1, 5, 21, 85, 341, 1365, 5461, 21845};
    for (int lev = 4; lev >= 0; --lev) {
        int lo = LIM[lev], nodes = LIM[lev + 1] - lo;
        for (int n = wid; n < nodes; n += 16)
            up_node(ws, t, g, lo + n, l, p, lane, Areg);
        __syncthreads();
    }
}

// ---- down-pass: root + levels 1..5, one block per gen ----
__global__ __launch_bounds__(1024) void k_down_small(float* __restrict__ ws, const int* __restrict__ t,
                                                     float* __restrict__ out) {
    int g = blockIdx.x, tid = threadIdx.x;
    __shared__ float sA[1024], sL[1024];
    if (tid < 1024) { sA[tid] = ws[OFF_SMA_T + (size_t)g * 1024 + tid]; sL[tid] = ws[OFF_SALA + (size_t)g * 1024 + tid]; }
    float acc = 0.0f;
    int i = tid & 15;
    if (tid < 16) {
        size_t nb = (size_t)g * NNODE * NC;
        float e = ws[OFF_BETA + nb + tid];  // eps[0] == beta[0] (aliased)
        int lab0 = t[0];
        acc += e * (ws[OFF_LSMPI + g * NC + tid] + ws[OFF_LSMB_T + ((size_t)g * NM + lab0) * NC + tid]);
    }
    __syncthreads();
    constexpr int LIM[9] = {0, 1, 5, 21, 85, 341, 1365, 5461, 21845};
    for (int lev = 1; lev <= 5; ++lev) {
        int lo = LIM[lev];
        int elems = (LIM[lev + 1] - lo) * 16;
        for (int idx = tid; idx < elems; idx += 1024) {
            int u = lo + (idx >> 4);
            int pa = (u - 1) >> 2, pos = (u - 1) & 3;
            size_t nb = ((size_t)g * NNODE + u) * NC;
            float bi_u = ws[OFF_BETA + nb + i];
            float pr = ws[OFF_PRIOR + nb + i];
            float bilv = ws[OFF_BETAIL + nb + i];
            float epv = ws[OFF_EPS + ((size_t)g * NNODE + pa) * NC + i];
            float w = epv * rcpf(bilv);
            float c0 = bi_u * rcpf(pr);
            float s1 = 0.0f, s2 = 0.0f;
#pragma unroll
            for (int j = 0; j < 16; ++j) {
                float wj = __shfl(w, j, 16);
                s1 += sA[(j * 4 + pos) * 16 + i] * wj;
                s2 += sL[(j * 4 + pos) * 16 + i] * wj;
            }
            float esum = c0 * s1;
            float tot = red16(esum);
            float ev = esum * rcpf(tot);
            ws[OFF_EPS + nb + i] = ev;
            int lab = t[u * 7];
            acc += c0 * s2 + ev * ws[OFF_LSMB_T + ((size_t)g * NM + lab) * NC + i];
        }
        __syncthreads();
    }
#pragma unroll
    for (int o = 1; o < 64; o <<= 1) acc += __shfl_xor(acc, o, 64);
    __shared__ float wsum[16];
    if ((tid & 63) == 0) wsum[tid >> 6] = acc;
    __syncthreads();
    if (tid == 0) {
        float s = 0.0f;
#pragma unroll
        for (int w2 = 0; w2 < 16; ++w2) s += wsum[w2];
        atomicAdd(&out[g], s);
    }
}

// ---- down big level (grid-stride, hoisted sm_a & sm_a*log tables) ----
__global__ __launch_bounds__(256) void k_down_big(float* __restrict__ ws, const int* __restrict__ t,
                                                  int lo, int elems, float* __restrict__ out) {
    int g = blockIdx.y, tid = threadIdx.x;
    int idx0 = blockIdx.x * 256 + tid;
    int stride = gridDim.x * 256;
    int i = tid & 15;
    int pos = (lo + (idx0 >> 4) - 1) & 3;
    float sAreg[16], sLreg[16];
#pragma unroll
    for (int j = 0; j < 16; ++j) {
        sAreg[j] = ws[OFF_SMA_T + (size_t)g * 1024 + (j * 4 + pos) * 16 + i];
        sLreg[j] = ws[OFF_SALA + (size_t)g * 1024 + (j * 4 + pos) * 16 + i];
    }
    float acc = 0.0f;
    for (int idx = idx0; idx < elems; idx += stride) {
        int u = lo + (idx >> 4);
        int pa = (u - 1) >> 2;
        size_t nb = ((size_t)g * NNODE + u) * NC;
        float bi_u = ws[OFF_BETA + nb + i];
        float pr = ws[OFF_PRIOR + nb + i];
        float bilv = ws[OFF_BETAIL + nb + i];
        float epv = ws[OFF_EPS + ((size_t)g * NNODE + pa) * NC + i];
        float w = epv * rcpf(bilv);
        float c0 = bi_u * rcpf(pr);
        float s1 = 0.0f, s2 = 0.0f;
#pragma unroll
        for (int j = 0; j < 16; ++j) {
            float wj = __shfl(w, j, 16);
            s1 += sAreg[j] * wj;
            s2 += sLreg[j] * wj;
        }
        float esum = c0 * s1;
        float tot = red16(esum);
        float ev = esum * rcpf(tot);
        ws[OFF_EPS + nb + i] = ev;
        int lab = t[u * 7];
        acc += c0 * s2 + ev * ws[OFF_LSMB_T + ((size_t)g * NM + lab) * NC + i];
    }
#pragma unroll
    for (int o = 1; o < 64; o <<= 1) acc += __shfl_xor(acc, o, 64);
    __shared__ float wsum[4];
    if ((tid & 63) == 0) wsum[tid >> 6] = acc;
    __syncthreads();
    if (tid == 0) atomicAdd(&out[g], wsum[0] + wsum[1] + wsum[2] + wsum[3]);
}

extern "C" void kernel_launch(void* const* d_in, const int* in_sizes, int n_in,
                              void* d_out, int out_size, void* d_ws, size_t ws_size,
                              hipStream_t stream) {
    const float* a = (const float*)d_in[0];
    const float* b = (const float*)d_in[1];
    const float* pi = (const float*)d_in[2];
    const int* t = (const int*)d_in[3];
    float* out = (float*)d_out;
    float* ws = (float*)d_ws;

    k_init<<<136, 256, 0, stream>>>(a, b, pi, ws, out);
    k_prior_small<<<NGEN, 256, 0, stream>>>(ws);
    k_prior_big<false><<<dim3(128, NGEN), 256, 0, stream>>>(ws, t, 1365, 4096 * 16);
    k_prior_big<true><<<dim3(256, NGEN), 256, 0, stream>>>(ws, t, 5461, 16384 * 16);
    k_up_big<<<dim3(256, NGEN), 256, 0, stream>>>(ws, t, 1365, 4096);  // lev6
    k_up_big<<<dim3(64, NGEN), 256, 0, stream>>>(ws, t, 341, 1024);    // lev5
    k_up_small<<<NGEN, 1024, 0, stream>>>(ws, t);                      // lev 4..0
    k_down_small<<<NGEN, 1024, 0, stream>>>(ws, t, out);               // root + lev 1..5
    k_down_big<<<dim3(64, NGEN), 256, 0, stream>>>(ws, t, 1365, 4096 * 16, out);
    k_down_big<<<dim3(256, NGEN), 256, 0, stream>>>(ws, t, 5461, 16384 * 16, out);
}

// Round 4
// 102.611 us; speedup vs baseline: 3.5794x; 1.9550x over previous
//
#include <hip/hip_runtime.h>

#define NGEN 8
#define NC 16
#define NM 256
#define NNODE 21845

// float-element offsets inside d_ws (total ~711 KB)
#define OFF_SMA_T  ((size_t)0)            // [g][j][l][i] sm_a            8192
#define OFF_SALA   ((size_t)8192)         // [g][j][l][i] sm_a*log(sm_a)  8192
#define OFF_SMA_U  ((size_t)16384)        // [g][c][l][p] sm_a (up)       8192
#define OFF_SMB_T  ((size_t)24576)        // [g][m][i]                    32768
#define OFF_LSMB_T ((size_t)57344)        // [g][m][i] log                32768
#define OFF_SMPI   ((size_t)90112)        // 128
#define OFF_LSMPI  ((size_t)90240)        // 128
#define OFF_LAB    ((size_t)90368)        // 21845 ints (label per node)
#define OFF_BETA4  ((size_t)112224)       // [g][256][16] beta at level-4 nodes
#define OFF_EPS4   ((size_t)144992)       // [g][256][16] eps  at level-4 nodes

__device__ __forceinline__ float red16(float v) {
    v += __shfl_xor(v, 1, 16);
    v += __shfl_xor(v, 2, 16);
    v += __shfl_xor(v, 4, 16);
    v += __shfl_xor(v, 8, 16);
    return v;
}
__device__ __forceinline__ float rcpf(float x) { return __builtin_amdgcn_rcpf(x); }

// up step for one node nd (wave-per-node; lane = l*16+p). Children in LDS.
__device__ __forceinline__ void up_step(const float (*Bch)[16], const float (*Pch)[16],
                                        float (*BILch)[16],           // nullptr => don't store
                                        float (*Bpar)[16], const float (*Ppar)[16],
                                        const float* smb, int lab, int nd, int l, int p,
                                        const float* Aup, bool storeBeta) {
    int ch = 4 * nd + l;
    float rv = Bch[ch][p] * rcpf(Pch[ch][p]);
    float bil = 0.f;
#pragma unroll
    for (int c = 0; c < 16; ++c) bil += __shfl(rv, c, 16) * Aup[c];
    if (BILch) BILch[ch][p] = bil;
    float t0 = bil * __shfl_xor(bil, 16);
    float aux = t0 * __shfl_xor(t0, 32);
    if (storeBeta) {
        float bi = aux * smb[(size_t)lab * 16 + p] * Ppar[nd][p];
        float ssum = red16(bi);
        if (l == 0) Bpar[nd][p] = bi * rcpf(ssum);
    }
}

// down step for one node nl (thread-per-(nl,i)). Returns likelihood contribution.
__device__ __forceinline__ float down_step(float (*Bown)[16], const float (*Pown)[16],
                                           const float (*BILown)[16], const float (*Epar)[16],
                                           int nl, int i, const float* Areg, const float* sLreg,
                                           const float* lsmb, int lab, bool writeE) {
    float w = Epar[nl >> 2][i] * rcpf(BILown[nl][i]);
    float c0 = Bown[nl][i] * rcpf(Pown[nl][i]);
    float s1 = 0.f, s2 = 0.f;
#pragma unroll
    for (int j = 0; j < 16; ++j) {
        float wj = __shfl(w, j, 16);
        s1 += Areg[j] * wj;
        s2 += sLreg[j] * wj;
    }
    float esum = c0 * s1;
    float tot = red16(esum);
    float ev = esum * rcpf(tot);
    if (writeE) Bown[nl][i] = ev;   // eps overwrites beta (own row only)
    return c0 * s2 + ev * lsmb[(size_t)lab * 16 + i];
}

// ---- init: softmax_b + labels (blocks 0..127), softmax_a + pi + zero (128..135) ----
__global__ __launch_bounds__(256) void k_init(const float* __restrict__ a,
                                              const float* __restrict__ b,
                                              const float* __restrict__ pi,
                                              const int* __restrict__ t,
                                              float* __restrict__ ws, float* __restrict__ out) {
    int bx = blockIdx.x, tid = threadIdx.x;
    if (bx < 128) {
        int gtid = bx * 256 + tid;
        if (gtid < NNODE) ((int*)(ws + OFF_LAB))[gtid] = t[gtid * 7];
        int g = bx >> 4, i = bx & 15, m = tid;
        float v = b[((size_t)(g * NC + i)) * NM + m];
        __shared__ float sred[256];
        sred[m] = v;
        __syncthreads();
        for (int s = 128; s > 0; s >>= 1) { if (m < s) sred[m] = fmaxf(sred[m], sred[m + s]); __syncthreads(); }
        float mx = sred[0];
        __syncthreads();
        float ex = expf(v - mx);
        sred[m] = ex;
        __syncthreads();
        for (int s = 128; s > 0; s >>= 1) { if (m < s) sred[m] += sred[m + s]; __syncthreads(); }
        float sum = sred[0];
        ws[OFF_SMB_T + ((size_t)g * NM + m) * NC + i] = ex / sum;
        ws[OFF_LSMB_T + ((size_t)g * NM + m) * NC + i] = v - mx - logf(sum);
        return;
    }
    int g = bx - 128;
    if (tid < 64) {
        int j = tid >> 2, l = tid & 3;
        size_t base = ((size_t)(g * NC) * NC + j) * 4 + l;  // a[g][i][j][l], i-stride 64
        float v[16];
        float mx = -1e30f;
#pragma unroll
        for (int i = 0; i < 16; ++i) { v[i] = a[base + (size_t)i * 64]; mx = fmaxf(mx, v[i]); }
        float e[16], s = 0.0f;
#pragma unroll
        for (int i = 0; i < 16; ++i) { e[i] = expf(v[i] - mx); s += e[i]; }
        float ls = logf(s), rs = 1.0f / s;
        size_t tb = ((size_t)(g * NC + j) * 4 + l) * NC;  // [g][j][l][*]
#pragma unroll
        for (int i = 0; i < 16; ++i) {
            float sm = e[i] * rs;
            float lg = v[i] - mx - ls;
            ws[OFF_SMA_T + tb + i] = sm;
            ws[OFF_SALA + tb + i] = sm * lg;
            ws[OFF_SMA_U + ((size_t)(g * NC + i) * 4 + l) * NC + j] = sm;  // [g][c][l][p]
        }
    } else if (tid == 64) {
        float v[16];
        float mx = -1e30f;
#pragma unroll
        for (int i = 0; i < 16; ++i) { v[i] = pi[g * NC + i]; mx = fmaxf(mx, v[i]); }
        float e[16], s = 0.0f;
#pragma unroll
        for (int i = 0; i < 16; ++i) { e[i] = expf(v[i] - mx); s += e[i]; }
        float ls = logf(s), rs = 1.0f / s;
#pragma unroll
        for (int i = 0; i < 16; ++i) {
            ws[OFF_SMPI + g * NC + i] = e[i] * rs;
            ws[OFF_LSMPI + g * NC + i] = v[i] - mx - ls;
        }
        out[g] = 0.0f;
    }
}

// ---- subtree common prologue: stage tables, labels, path-prior -> P4, subtree prior+leaf ----
// (shared structurally by k_sub_up / k_sub_down via code duplication below)

__global__ __launch_bounds__(256) void k_sub_up(float* __restrict__ ws) {
    int s = blockIdx.x, g = blockIdx.y, tid = threadIdx.x;
    int v = 85 + s;
    int i = tid & 15, grp = tid >> 4, pos = grp & 3;
    int lane = tid & 63, wv = tid >> 6;
    int l = lane >> 4, p = lane & 15;
    const float* sAg = ws + OFF_SMA_T + (size_t)g * 1024;
    const float* Aug = ws + OFF_SMA_U + (size_t)g * 1024;
    const float* smb = ws + OFF_SMB_T + (size_t)g * 4096;
    const int* LAB = (const int*)(ws + OFF_LAB);

    __shared__ float sAs[1024], Aus[1024];
    __shared__ float P5[4][16], P6[16][16], P7[64][16];
    __shared__ float B5[4][16], B6[16][16], B7[64][16];
    __shared__ float P4[16];
    __shared__ int labs[85];

    for (int k = tid; k < 1024; k += 256) { sAs[k] = sAg[k]; Aus[k] = Aug[k]; }
    if (tid < 64) labs[21 + tid] = LAB[64 * v + 21 + tid];
    else if (tid < 80) labs[5 + (tid - 64)] = LAB[16 * v + 5 + (tid - 64)];
    else if (tid < 84) labs[1 + (tid - 80)] = LAB[4 * v + 1 + (tid - 80)];
    else if (tid == 84) labs[0] = LAB[v];
    __syncthreads();

    float Areg[16], Aup[16];
#pragma unroll
    for (int j = 0; j < 16; ++j) Areg[j] = sAs[(j * 4 + pos) * 16 + i];
#pragma unroll
    for (int c = 0; c < 16; ++c) Aup[c] = Aus[(c * 4 + l) * 16 + p];

    if (tid < 16) {  // path prior root -> v
        int v3 = (v - 1) >> 2, v2 = (v3 - 1) >> 2, v1 = (v2 - 1) >> 2;
        int chain[4] = {v1, v2, v3, v};
        float pr = ws[OFF_SMPI + g * 16 + i];
#pragma unroll
        for (int k = 0; k < 4; ++k) {
            int pk = (chain[k] - 1) & 3;
            float sacc = 0.f;
#pragma unroll
            for (int j = 0; j < 16; ++j) sacc += sAs[(j * 4 + pk) * 16 + i] * __shfl(pr, j, 16);
            pr = sacc;
        }
        P4[i] = pr;
    }
    __syncthreads();
    if (tid < 64) {  // prior lev5
        float pv = P4[i];
        float sacc = 0.f;
#pragma unroll
        for (int j = 0; j < 16; ++j) sacc += Areg[j] * __shfl(pv, j, 16);
        P5[grp][i] = sacc;
    }
    __syncthreads();
    {  // prior lev6
        float pv = P5[grp >> 2][i];
        float sacc = 0.f;
#pragma unroll
        for (int j = 0; j < 16; ++j) sacc += Areg[j] * __shfl(pv, j, 16);
        P6[grp][i] = sacc;
    }
    __syncthreads();
    for (int k = 0; k < 4; ++k) {  // prior lev7 + leaf beta
        int nl = grp + 16 * k;
        float pv = P6[nl >> 2][i];
        float sacc = 0.f;
#pragma unroll
        for (int j = 0; j < 16; ++j) sacc += Areg[j] * __shfl(pv, j, 16);
        P7[nl][i] = sacc;
        float bl = smb[(size_t)labs[21 + nl] * 16 + i] * sacc;
        float ssum = red16(bl);
        B7[nl][i] = bl * rcpf(ssum);
    }
    __syncthreads();
    for (int r = 0; r < 4; ++r)  // up lev6 (16 nodes)
        up_step(B7, P7, nullptr, B6, P6, smb, labs[5 + (wv + 4 * r)], wv + 4 * r, l, p, Aup, true);
    __syncthreads();
    up_step(B6, P6, nullptr, B5, P5, smb, labs[1 + wv], wv, l, p, Aup, true);  // up lev5 (4 nodes)
    __syncthreads();
    if (wv == 0) {  // up lev4 -> global beta4
        float rv = B5[l][p] * rcpf(P5[l][p]);
        float bil = 0.f;
#pragma unroll
        for (int c = 0; c < 16; ++c) bil += __shfl(rv, c, 16) * Aup[c];
        float t0 = bil * __shfl_xor(bil, 16);
        float aux = t0 * __shfl_xor(t0, 32);
        float bi = aux * smb[(size_t)labs[0] * 16 + p] * P4[p];
        float ssum = red16(bi);
        if (l == 0) ws[OFF_BETA4 + ((size_t)g * 256 + s) * 16 + p] = bi * rcpf(ssum);
    }
}

// ---- top levels: prior 1..4, up 3..0, root, down 1..4; one block per gen ----
__global__ __launch_bounds__(1024) void k_top(float* __restrict__ ws, float* __restrict__ out) {
    int g = blockIdx.x, tid = threadIdx.x;
    int i = tid & 15, grp = tid >> 4, pos = grp & 3;
    int lane = tid & 63, wv = tid >> 6;  // 16 waves
    int l = lane >> 4, p = lane & 15;
    const float* sAg = ws + OFF_SMA_T + (size_t)g * 1024;
    const float* sLg = ws + OFF_SALA + (size_t)g * 1024;
    const float* Aug = ws + OFF_SMA_U + (size_t)g * 1024;
    const float* smb = ws + OFF_SMB_T + (size_t)g * 4096;
    const float* lsmb = ws + OFF_LSMB_T + (size_t)g * 4096;
    const float* beta4 = ws + OFF_BETA4 + (size_t)g * 4096;
    float* eps4 = ws + OFF_EPS4 + (size_t)g * 4096;
    const int* LAB = (const int*)(ws + OFF_LAB);

    __shared__ float Pt[341][16], Bt[341][16], BILt[341][16];
    __shared__ int labt[341];
    __shared__ float wsum[16];

    float Areg[16], Aup[16], sLreg[16];
#pragma unroll
    for (int j = 0; j < 16; ++j) {
        Areg[j] = sAg[(j * 4 + pos) * 16 + i];
        sLreg[j] = sLg[(j * 4 + pos) * 16 + i];
    }
#pragma unroll
    for (int c = 0; c < 16; ++c) Aup[c] = Aug[(c * 4 + l) * 16 + p];
    if (tid < 341) labt[tid] = LAB[tid];
    if (tid < 16) Pt[0][i] = ws[OFF_SMPI + g * 16 + i];
    __syncthreads();
    // prior levels 1..4 (rows 1..340)
    if (grp < 4) {
        float pv = Pt[0][i];
        float s = 0.f;
#pragma unroll
        for (int j = 0; j < 16; ++j) s += Areg[j] * __shfl(pv, j, 16);
        Pt[1 + grp][i] = s;
    }
    __syncthreads();
    if (grp < 16) {
        float pv = Pt[1 + (grp >> 2)][i];
        float s = 0.f;
#pragma unroll
        for (int j = 0; j < 16; ++j) s += Areg[j] * __shfl(pv, j, 16);
        Pt[5 + grp][i] = s;
    }
    __syncthreads();
    {
        float pv = Pt[5 + (grp >> 2)][i];
        float s = 0.f;
#pragma unroll
        for (int j = 0; j < 16; ++j) s += Areg[j] * __shfl(pv, j, 16);
        Pt[21 + grp][i] = s;
    }
    __syncthreads();
    for (int k = 0; k < 4; ++k) {
        int nl = grp + 64 * k;
        float pv = Pt[21 + (nl >> 2)][i];
        float s = 0.f;
#pragma unroll
        for (int j = 0; j < 16; ++j) s += Areg[j] * __shfl(pv, j, 16);
        Pt[85 + nl][i] = s;
    }
    __syncthreads();
    // up lev3 (64 nodes; children beta from global beta4)
    for (int r = 0; r < 4; ++r) {
        int nd = wv + 16 * r;
        int chl = 4 * nd + l;  // lev4 local
        float rv = beta4[(size_t)chl * 16 + p] * rcpf(Pt[85 + chl][p]);
        float bil = 0.f;
#pragma unroll
        for (int c = 0; c < 16; ++c) bil += __shfl(rv, c, 16) * Aup[c];
        BILt[85 + chl][p] = bil;
        float t0 = bil * __shfl_xor(bil, 16);
        float aux = t0 * __shfl_xor(t0, 32);
        float bi = aux * smb[(size_t)labt[21 + nd] * 16 + p] * Pt[21 + nd][p];
        float ssum = red16(bi);
        if (l == 0) Bt[21 + nd][p] = bi * rcpf(ssum);
    }
    __syncthreads();
    {  // up lev2 (16 nodes)
        int nd = wv, ch = 21 + 4 * nd + l;
        float rv = Bt[ch][p] * rcpf(Pt[ch][p]);
        float bil = 0.f;
#pragma unroll
        for (int c = 0; c < 16; ++c) bil += __shfl(rv, c, 16) * Aup[c];
        BILt[ch][p] = bil;
        float t0 = bil * __shfl_xor(bil, 16);
        float aux = t0 * __shfl_xor(t0, 32);
        float bi = aux * smb[(size_t)labt[5 + nd] * 16 + p] * Pt[5 + nd][p];
        float ssum = red16(bi);
        if (l == 0) Bt[5 + nd][p] = bi * rcpf(ssum);
    }
    __syncthreads();
    if (wv < 4) {  // up lev1 (4 nodes)
        int nd = wv, ch = 5 + 4 * nd + l;
        float rv = Bt[ch][p] * rcpf(Pt[ch][p]);
        float bil = 0.f;
#pragma unroll
        for (int c = 0; c < 16; ++c) bil += __shfl(rv, c, 16) * Aup[c];
        BILt[ch][p] = bil;
        float t0 = bil * __shfl_xor(bil, 16);
        float aux = t0 * __shfl_xor(t0, 32);
        float bi = aux * smb[(size_t)labt[1 + nd] * 16 + p] * Pt[1 + nd][p];
        float ssum = red16(bi);
        if (l == 0) Bt[1 + nd][p] = bi * rcpf(ssum);
    }
    __syncthreads();
    if (wv == 0) {  // up lev0 (root)
        int ch = 1 + l;
        float rv = Bt[ch][p] * rcpf(Pt[ch][p]);
        float bil = 0.f;
#pragma unroll
        for (int c = 0; c < 16; ++c) bil += __shfl(rv, c, 16) * Aup[c];
        BILt[ch][p] = bil;
        float t0 = bil * __shfl_xor(bil, 16);
        float aux = t0 * __shfl_xor(t0, 32);
        float bi = aux * smb[(size_t)labt[0] * 16 + p] * Pt[0][p];
        float ssum = red16(bi);
        if (l == 0) Bt[0][p] = bi * rcpf(ssum);
    }
    __syncthreads();
    float acc = 0.f;
    if (tid < 16)  // root: eps0 = beta0 (in place); pi + b terms
        acc += Bt[0][i] * (ws[OFF_LSMPI + g * 16 + i] + lsmb[(size_t)labt[0] * 16 + i]);
    // down levels 1..3 (in-LDS), then lev4 (beta from global, eps -> global)
    if (grp < 4) {
        int row = 1 + grp;
        float w = Bt[0][i] * rcpf(BILt[row][i]);
        float c0 = Bt[row][i] * rcpf(Pt[row][i]);
        float s1 = 0.f, s2 = 0.f;
#pragma unroll
        for (int j = 0; j < 16; ++j) { float wj = __shfl(w, j, 16); s1 += Areg[j] * wj; s2 += sLreg[j] * wj; }
        float esum = c0 * s1, tot = red16(esum), ev = esum * rcpf(tot);
        Bt[row][i] = ev;
        acc += c0 * s2 + ev * lsmb[(size_t)labt[row] * 16 + i];
    }
    __syncthreads();
    if (grp < 16) {
        int row = 5 + grp, pa = 1 + (grp >> 2);
        float w = Bt[pa][i] * rcpf(BILt[row][i]);
        float c0 = Bt[row][i] * rcpf(Pt[row][i]);
        float s1 = 0.f, s2 = 0.f;
#pragma unroll
        for (int j = 0; j < 16; ++j) { float wj = __shfl(w, j, 16); s1 += Areg[j] * wj; s2 += sLreg[j] * wj; }
        float esum = c0 * s1, tot = red16(esum), ev = esum * rcpf(tot);
        Bt[row][i] = ev;
        acc += c0 * s2 + ev * lsmb[(size_t)labt[row] * 16 + i];
    }
    __syncthreads();
    {
        int row = 21 + grp, pa = 5 + (grp >> 2);
        float w = Bt[pa][i] * rcpf(BILt[row][i]);
        float c0 = Bt[row][i] * rcpf(Pt[row][i]);
        float s1 = 0.f, s2 = 0.f;
#pragma unroll
        for (int j = 0; j < 16; ++j) { float wj = __shfl(w, j, 16); s1 += Areg[j] * wj; s2 += sLreg[j] * wj; }
        float esum = c0 * s1, tot = red16(esum), ev = esum * rcpf(tot);
        Bt[row][i] = ev;
        acc += c0 * s2 + ev * lsmb[(size_t)labt[row] * 16 + i];
    }
    __syncthreads();
    for (int k = 0; k < 4; ++k) {
        int nl = grp + 64 * k;
        int row = 85 + nl, pa = 21 + (nl >> 2);
        float w = Bt[pa][i] * rcpf(BILt[row][i]);
        float c0 = beta4[(size_t)nl * 16 + i] * rcpf(Pt[row][i]);
        float s1 = 0.f, s2 = 0.f;
#pragma unroll
        for (int j = 0; j < 16; ++j) { float wj = __shfl(w, j, 16); s1 += Areg[j] * wj; s2 += sLreg[j] * wj; }
        float esum = c0 * s1, tot = red16(esum), ev = esum * rcpf(tot);
        eps4[(size_t)nl * 16 + i] = ev;
        acc += c0 * s2 + ev * lsmb[(size_t)labt[row] * 16 + i];
    }
#pragma unroll
    for (int o = 1; o < 64; o <<= 1) acc += __shfl_xor(acc, o);
    if ((tid & 63) == 0) wsum[tid >> 6] = acc;
    __syncthreads();
    if (tid == 0) {
        float stot = 0.f;
#pragma unroll
        for (int w2 = 0; w2 < 16; ++w2) stot += wsum[w2];
        atomicAdd(&out[g], stot);
    }
}

// ---- subtree down: recompute prior/beta/bil locally, then eps + likelihood ----
__global__ __launch_bounds__(256) void k_sub_down(float* __restrict__ ws, float* __restrict__ out) {
    int s = blockIdx.x, g = blockIdx.y, tid = threadIdx.x;
    int v = 85 + s;
    int i = tid & 15, grp = tid >> 4, pos = grp & 3;
    int lane = tid & 63, wv = tid >> 6;
    int l = lane >> 4, p = lane & 15;
    const float* sAg = ws + OFF_SMA_T + (size_t)g * 1024;
    const float* sLg = ws + OFF_SALA + (size_t)g * 1024;
    const float* Aug = ws + OFF_SMA_U + (size_t)g * 1024;
    const float* smb = ws + OFF_SMB_T + (size_t)g * 4096;
    const float* lsmb = ws + OFF_LSMB_T + (size_t)g * 4096;
    const int* LAB = (const int*)(ws + OFF_LAB);

    __shared__ float sAs[1024], sLs[1024], Aus[1024];
    __shared__ float P5[4][16], P6[16][16], P7[64][16];
    __shared__ float B5[4][16], B6[16][16], B7[64][16];
    __shared__ float BIL5[4][16], BIL6[16][16], BIL7[64][16];
    __shared__ float P4[16], E4[16];
    __shared__ int labs[85];
    __shared__ float wsum[4];

    for (int k = tid; k < 1024; k += 256) { sAs[k] = sAg[k]; sLs[k] = sLg[k]; Aus[k] = Aug[k]; }
    if (tid < 64) labs[21 + tid] = LAB[64 * v + 21 + tid];
    else if (tid < 80) labs[5 + (tid - 64)] = LAB[16 * v + 5 + (tid - 64)];
    else if (tid < 84) labs[1 + (tid - 80)] = LAB[4 * v + 1 + (tid - 80)];
    else if (tid == 84) labs[0] = LAB[v];
    else if (tid >= 96 && tid < 112) E4[tid - 96] = ws[OFF_EPS4 + ((size_t)g * 256 + s) * 16 + (tid - 96)];
    __syncthreads();

    float Areg[16], Aup[16], sLreg[16];
#pragma unroll
    for (int j = 0; j < 16; ++j) {
        Areg[j] = sAs[(j * 4 + pos) * 16 + i];
        sLreg[j] = sLs[(j * 4 + pos) * 16 + i];
    }
#pragma unroll
    for (int c = 0; c < 16; ++c) Aup[c] = Aus[(c * 4 + l) * 16 + p];

    if (tid < 16) {
        int v3 = (v - 1) >> 2, v2 = (v3 - 1) >> 2, v1 = (v2 - 1) >> 2;
        int chain[4] = {v1, v2, v3, v};
        float pr = ws[OFF_SMPI + g * 16 + i];
#pragma unroll
        for (int k = 0; k < 4; ++k) {
            int pk = (chain[k] - 1) & 3;
            float sacc = 0.f;
#pragma unroll
            for (int j = 0; j < 16; ++j) sacc += sAs[(j * 4 + pk) * 16 + i] * __shfl(pr, j, 16);
            pr = sacc;
        }
        P4[i] = pr;
    }
    __syncthreads();
    if (tid < 64) {
        float pv = P4[i];
        float sacc = 0.f;
#pragma unroll
        for (int j = 0; j < 16; ++j) sacc += Areg[j] * __shfl(pv, j, 16);
        P5[grp][i] = sacc;
    }
    __syncthreads();
    {
        float pv = P5[grp >> 2][i];
        float sacc = 0.f;
#pragma unroll
        for (int j = 0; j < 16; ++j) sacc += Areg[j] * __shfl(pv, j, 16);
        P6[grp][i] = sacc;
    }
    __syncthreads();
    for (int k = 0; k < 4; ++k) {
        int nl = grp + 16 * k;
        float pv = P6[nl >> 2][i];
        float sacc = 0.f;
#pragma unroll
        for (int j = 0; j < 16; ++j) sacc += Areg[j] * __shfl(pv, j, 16);
        P7[nl][i] = sacc;
        float bl = smb[(size_t)labs[21 + nl] * 16 + i] * sacc;
        float ssum = red16(bl);
        B7[nl][i] = bl * rcpf(ssum);
    }
    __syncthreads();
    for (int r = 0; r < 4; ++r)
        up_step(B7, P7, BIL7, B6, P6, smb, labs[5 + (wv + 4 * r)], wv + 4 * r, l, p, Aup, true);
    __syncthreads();
    up_step(B6, P6, BIL6, B5, P5, smb, labs[1 + wv], wv, l, p, Aup, true);
    __syncthreads();
    if (wv == 0) {  // up lev4: only need children bil
        float rv = B5[l][p] * rcpf(P5[l][p]);
        float bil = 0.f;
#pragma unroll
        for (int c = 0; c < 16; ++c) bil += __shfl(rv, c, 16) * Aup[c];
        BIL5[l][p] = bil;
    }
    __syncthreads();
    // down sweep with fused likelihood
    float acc = 0.f;
    if (tid < 64)
        acc += down_step(B5, P5, BIL5, (const float(*)[16])E4, grp, i, Areg, sLreg, lsmb, labs[1 + grp], true);
    __syncthreads();
    acc += down_step(B6, P6, BIL6, (const float(*)[16])B5, grp, i, Areg, sLreg, lsmb, labs[5 + grp], true);
    __syncthreads();
    for (int k = 0; k < 4; ++k) {
        int nl = grp + 16 * k;
        acc += down_step(B7, P7, BIL7, (const float(*)[16])B6, nl, i, Areg, sLreg, lsmb, labs[21 + nl], false);
    }
#pragma unroll
    for (int o = 1; o < 64; o <<= 1) acc += __shfl_xor(acc, o);
    if ((tid & 63) == 0) wsum[tid >> 6] = acc;
    __syncthreads();
    if (tid == 0) atomicAdd(&out[g], wsum[0] + wsum[1] + wsum[2] + wsum[3]);
}

extern "C" void kernel_launch(void* const* d_in, const int* in_sizes, int n_in,
                              void* d_out, int out_size, void* d_ws, size_t ws_size,
                              hipStream_t stream) {
    const float* a = (const float*)d_in[0];
    const float* b = (const float*)d_in[1];
    const float* pi = (const float*)d_in[2];
    const int* t = (const int*)d_in[3];
    float* out = (float*)d_out;
    float* ws = (float*)d_ws;

    k_init<<<136, 256, 0, stream>>>(a, b, pi, t, ws, out);
    k_sub_up<<<dim3(256, NGEN), 256, 0, stream>>>(ws);
    k_top<<<NGEN, 1024, 0, stream>>>(ws, out);
    k_sub_down<<<dim3(256, NGEN), 256, 0, stream>>>(ws, out);
}